// Round 10
// baseline (428.580 us; speedup 1.0000x reference)
//
#include <hip/hip_runtime.h>

// LaplacianPyramidLoss: loss = sum_l mean(|pyr(x)[l] - pyr(t)[l]|)
// Linearity: pyr(x)-pyr(t) = pyr(x-t) -> ONE pyramid of d=x-t.
// R10 = R9 with ONE fix: issue(next tile) BEFORE ds_write(cur tile)
// (T14 issue-early/write-late). R9 issued next's loads AFTER the write,
// so a tile's loads aged only the ~300-600cy compute phase before their
// vmcnt wait -- every wave ate ~600cy of HBM latency per tile. With the
// reorder + double prefetch registers, the compiler's scoreboard emits
// vmcnt(6) (next's 6 loads stay in flight) and loads age a full period.
// Level 2 fuses mean(|down2|): down2 never hits HBM.

constexpr int THREADS = 256;
constexpr int TC = 32;              // down cols per tile
constexpr int TR = 16;              // down rows per tile
constexpr int ROWS = 2*TR + 3;      // 35 input rows (5x5 halo)
constexpr int COLS = 2*TC + 8;      // 72 float row stride (16B-aligned halo)
constexpr int SEG4 = COLS/4;        // 18 float4 per row
constexpr int TOT4 = ROWS*SEG4;     // 630 float4 per tile
constexpr int KLOAD = (TOT4 + THREADS - 1)/THREADS;   // 3 float4/thread
constexpr int HR = 11;              // h rows per wave (4 down rows + halo)
constexpr int NBLK = 1536;          // persistent: 6 blocks/CU x 256 CU

template <bool FUSE, bool LAST, bool WRITE_DOWN>
__global__ __launch_bounds__(THREADS, 6)   // 6 blocks/CU -> VGPR <= 85
void lap_level(const float* __restrict__ A,    // x (lvl0) or cur
               const float* __restrict__ Bp,   // t (lvl0) or nullptr
               const float* __restrict__ w25,  // 5x5 gaussian (channel 0)
               float* __restrict__ down,       // H/2 x W/2 (if WRITE_DOWN)
               float* __restrict__ P,          // partials P[lvl*8+s], [24+s]
               int H, int W, int ntx, int ntxy, int ntiles, int level)
{
    __shared__ __align__(16) float sdD[2][ROWS*COLS];  // 20.2 KB ping-pong
    __shared__ float sdH[4][HR*TC];                    // 5.6 KB per-wave h
    __shared__ float wsl[4], wsd[4];

    const int tid  = threadIdx.x;
    const int wv   = tid >> 6, lane = tid & 63;
    const int Hd = H >> 1, Wd = W >> 1;

    // exact 1D factor: g_i = row-sum of w25 (k = g g^T since sum k = T^2)
    float g0, g1, g2, g3, g4;
    {
        float gg[5];
#pragma unroll
        for (int i = 0; i < 5; ++i) {
            float s = 0.f;
#pragma unroll
            for (int j = 0; j < 5; ++j) s += w25[i*5 + j];
            gg[i] = s;
        }
        g0 = gg[0]; g1 = gg[1]; g2 = gg[2]; g3 = gg[3]; g4 = gg[4];
    }

    // hoisted staging coords (tid-only)
    int rr_[KLOAD], cc_[KLOAD];
#pragma unroll
    for (int k = 0; k < KLOAD; ++k) {
        const int idx = tid + k*THREADS;
        rr_[k] = idx / SEG4;
        cc_[k] = idx - rr_[k]*SEG4;
    }

    float lsum = 0.f, dsum = 0.f;
    float4 va0[KLOAD], vb0[KLOAD], va1[KLOAD], vb1[KLOAD];
    int cur = blockIdx.x;
    int p = 0;

    auto issue = [&](int t, float4 (&va)[KLOAD], float4 (&vb)[KLOAD]) {
        const int n   = t / ntxy;
        const int rem = t - n*ntxy;
        const int ty  = rem / ntx;
        const int tx  = rem - ty*ntx;
        const int gy0 = 2*ty*TR - 2;
        const int gx0 = 2*tx*TC - 4;        // 16B-aligned halo start
        const size_t ib = (size_t)n * H * W;
#pragma unroll
        for (int k = 0; k < KLOAD; ++k) {
            const int gy = gy0 + rr_[k];
            const int gx = gx0 + 4*cc_[k];  // W%4==0 -> float4 all-in/all-out
            const bool ok = (rr_[k] < ROWS) & ((unsigned)gy < (unsigned)H)
                                            & ((unsigned)gx < (unsigned)W);
            va[k] = make_float4(0.f, 0.f, 0.f, 0.f);
            if (FUSE) vb[k] = make_float4(0.f, 0.f, 0.f, 0.f);
            if (ok) {
                const size_t off = ib + (size_t)gy*W + gx;
                va[k] = *(const float4*)(A + off);
                if (FUSE) vb[k] = *(const float4*)(Bp + off);
            }
        }
    };

    auto write_lds = [&](int pp, float4 (&va)[KLOAD], float4 (&vb)[KLOAD]) {
#pragma unroll
        for (int k = 0; k < KLOAD; ++k) {
            if (rr_[k] < ROWS) {
                float4 d = va[k];
                if (FUSE) { d.x -= vb[k].x; d.y -= vb[k].y;
                            d.z -= vb[k].z; d.w -= vb[k].w; }
                *(float4*)&sdD[pp][rr_[k]*COLS + 4*cc_[k]] = d;
            }
        }
    };

    auto compute = [&](int t, int pp) {
        const int n   = t / ntxy;
        const int rem = t - n*ntxy;
        const int ty  = rem / ntx;
        const int tx  = rem - ty*ntx;
        const int oy0 = ty*TR, ox0 = tx*TC;
        const float* dd = sdD[pp];
        float* hh = sdH[wv];
        const int hb = 8*wv;            // wave's input-row base (4 down rows)

        // h-pass: 11 rows x 32 even-cols, wave-private region
#pragma unroll
        for (int k = 0; k < (HR*TC + 63)/64; ++k) {
            const int idx = lane + 64*k;
            if (idx < HR*TC) {
                const int hr = idx >> 5, hc = idx & 31;
                const float* dr = &dd[(hb + hr)*COLS + 2*hc + 2];
                float a = g0*dr[0];
                a = fmaf(g1, dr[1], a);
                a = fmaf(g2, dr[2], a);
                a = fmaf(g3, dr[3], a);
                a = fmaf(g4, dr[4], a);
                hh[hr*TC + hc] = a;
            }
        }
        // v-pass: 2 outputs per lane (rows rsub, rsub+2 of wave's 4)
        const int ccx = lane & 31, rsub = lane >> 5;
#pragma unroll
        for (int q = 0; q < 2; ++q) {
            const int lr = rsub + 2*q;                // 0..3
            float acc = g0*hh[(2*lr)*TC + ccx];
            acc = fmaf(g1, hh[(2*lr+1)*TC + ccx], acc);
            acc = fmaf(g2, hh[(2*lr+2)*TC + ccx], acc);
            acc = fmaf(g3, hh[(2*lr+3)*TC + ccx], acc);
            acc = fmaf(g4, hh[(2*lr+4)*TC + ccx], acc);
            if (WRITE_DOWN) {
                const int gr = oy0 + 4*wv + lr;
                down[(size_t)n*Hd*Wd + (size_t)gr*Wd + (ox0 + ccx)] = acc;
            }
            // lap = cur - up(down): 2x2 input block of this down value
            const float* cr = &dd[(hb + 2*lr + 2)*COLS + 2*ccx + 4];
            lsum += fabsf(cr[0]    - acc) + fabsf(cr[1]      - acc)
                  + fabsf(cr[COLS] - acc) + fabsf(cr[COLS+1] - acc);
            if (LAST) dsum += fabsf(acc);
        }
    };

    if (cur < ntiles) {
        issue(cur, va0, vb0);
        bool useBuf0 = true;
        for (;;) {
            const int nxt = cur + NBLK;     // gridDim.x == NBLK
            // ---- T14: issue NEXT tile FIRST, then write cur's registers ----
            // compiler scoreboard -> vmcnt(6) before ds_write: next's loads
            // stay in flight; cur's loads have aged a full loop period.
            if (useBuf0) {
                if (nxt < ntiles) issue(nxt, va1, vb1);
                write_lds(p, va0, vb0);
            } else {
                if (nxt < ntiles) issue(nxt, va0, vb0);
                write_lds(p, va1, vb1);
            }
            asm volatile("s_waitcnt lgkmcnt(0)" ::: "memory");
            __builtin_amdgcn_s_barrier();
            __builtin_amdgcn_sched_barrier(0);

            compute(cur, p);

            if (nxt >= ntiles) break;
            cur = nxt; p ^= 1; useBuf0 = !useBuf0;
        }
    }

    // ---- wave reduce -> block reduce -> one spread atomic per level ----
#pragma unroll
    for (int off = 32; off > 0; off >>= 1) {
        lsum += __shfl_down(lsum, off);
        if (LAST) dsum += __shfl_down(dsum, off);
    }
    if (lane == 0) { wsl[wv] = lsum; if (LAST) wsd[wv] = dsum; }
    __syncthreads();
    if (tid == 0) {
        atomicAdd(&P[level*8 + (blockIdx.x & 7)], wsl[0]+wsl[1]+wsl[2]+wsl[3]);
        if (LAST)
            atomicAdd(&P[24 + (blockIdx.x & 7)], wsd[0]+wsd[1]+wsd[2]+wsd[3]);
    }
}

__global__ void finalize_kernel(const float* __restrict__ P,
                                float* __restrict__ out,
                                float inv0, float inv1, float inv2, float inv3)
{
    float s0 = 0.f, s1 = 0.f, s2 = 0.f, s3 = 0.f;
#pragma unroll
    for (int i = 0; i < 8; ++i) {
        s0 += P[i]; s1 += P[8+i]; s2 += P[16+i]; s3 += P[24+i];
    }
    out[0] = s0*inv0 + s1*inv1 + s2*inv2 + s3*inv3;
}

extern "C" void kernel_launch(void* const* d_in, const int* in_sizes, int n_in,
                              void* d_out, int out_size, void* d_ws, size_t ws_size,
                              hipStream_t stream)
{
    const float* x   = (const float*)d_in[0];
    const float* t   = (const float*)d_in[1];
    const float* ker = (const float*)d_in[2];  // (13,1,5,5); channels identical
    float* out = (float*)d_out;

    constexpr int B = 16, C = 13, H = 512, W = 512;
    constexpr int N = B * C;  // 208 image-channels

    // ws: [32 floats partials (pad 256B)] [down0: N*256*256] [down1: N*128*128]
    float* P     = (float*)d_ws;
    float* down0 = (float*)((char*)d_ws + 256);
    float* down1 = down0 + (size_t)N * (H/2) * (W/2);

    hipMemsetAsync(P, 0, 32 * sizeof(float), stream);

    dim3 blk(THREADS);
    // level 0: d = x-t (fused at LDS write), 512 -> down0 256
    {
        const int ntx = (W/2)/TC, ntxy = ntx * ((H/2)/TR);   // 8 x 16 = 128
        lap_level<true, false, true><<<dim3(NBLK), blk, 0, stream>>>(
            x, t, ker, down0, P, H, W, ntx, ntxy, ntxy*N, 0);
    }
    // level 1: down0 256 -> down1 128
    {
        const int ntx = (W/4)/TC, ntxy = ntx * ((H/4)/TR);   // 4 x 8 = 32
        lap_level<false, false, true><<<dim3(NBLK), blk, 0, stream>>>(
            down0, nullptr, ker, down1, P, H/2, W/2, ntx, ntxy, ntxy*N, 1);
    }
    // level 2: down1 128 -> 64 (in-register), fuses level-3 mean(|down2|)
    {
        const int ntx = (W/8)/TC, ntxy = ntx * ((H/8)/TR);   // 2 x 4 = 8
        lap_level<false, true, false><<<dim3(NBLK), blk, 0, stream>>>(
            down1, nullptr, ker, nullptr, P, H/4, W/4, ntx, ntxy, ntxy*N, 2);
    }

    const float inv0 = 1.0f / ((float)N * H * W);
    const float inv1 = 1.0f / ((float)N * (H/2) * (W/2));
    const float inv2 = 1.0f / ((float)N * (H/4) * (W/4));
    const float inv3 = 1.0f / ((float)N * (H/8) * (W/8));
    finalize_kernel<<<1, 1, 0, stream>>>(P, out, inv0, inv1, inv2, inv3);
}

// Round 11
// 211.509 us; speedup vs baseline: 2.0263x; 2.0263x over previous
//
#include <hip/hip_runtime.h>

// LaplacianPyramidLoss: loss = sum_l mean(|pyr(x)[l] - pyr(t)[l]|)
// Linearity: pyr(x)-pyr(t) = pyr(x-t) -> ONE pyramid of d=x-t.
// R11: persistent blocks + DOUBLE-BUFFERED global_load_lds pipeline.
// R10 proved issue-early ordering reaches 3.96 TB/s but register prefetch
// spilled to scratch (WRITE_SIZE 480 MB). gload_lds gives prefetch depth
// with ZERO VGPR cost: issue next tile (fire-and-forget) -> compute cur
// -> vmcnt(0)+barrier (loads age the whole compute phase). No ALU on the
// staging path -> level 0 stages x,t separately, subtracts in h-pass
// (h(x-t) = h(x)-h(t)); borders exact via clamped addresses + zeroed taps.
// Level 2 fuses mean(|down2|): down2 never touches HBM.

constexpr int THREADS = 256;
constexpr int TC = 32, TR = 16;       // down outputs per tile
constexpr int ROWS = 2*TR + 3;        // 35 input rows (5x5 halo)
constexpr int COLS = 2*TC + 8;        // 72 float stride (16B-aligned halo)
constexpr int SEG4 = COLS/4;          // 18 float4 per row
constexpr int TOT4 = ROWS*SEG4;       // 630 float4 per tile
constexpr int WOPS = (TOT4 + 63)/64;  // 10 wave-ops (64 lanes x 16B)
constexpr int WREG = WOPS*64*4;       // 2560-float staged region (tail unused)
constexpr int HR = 11;                // h rows per wave (4 down rows + halo)

__device__ inline void gload_lds16(const float* g, float* l) {
    auto g1 = (const __attribute__((address_space(1))) void*)g;
    auto l3 = (__attribute__((address_space(3))) void*)l;
    __builtin_amdgcn_global_load_lds(g1, l3, 16, 0, 0);
}

template <int MW, bool FUSE, bool LAST, bool WRITE_DOWN>
__global__ __launch_bounds__(THREADS, MW)
void lap_level(const float* __restrict__ A,    // x (lvl0) or cur
               const float* __restrict__ Bp,   // t (lvl0) or nullptr
               const float* __restrict__ w25,  // 5x5 gaussian (channel 0)
               float* __restrict__ down,       // H/2 x W/2 (if WRITE_DOWN)
               float* __restrict__ P,          // partials P[lvl*8+s], [24+s]
               int H, int W, int ntx, int nty, int ntiles, int level)
{
    __shared__ __align__(16) float sdA[2][WREG];
    __shared__ __align__(16) float sdB[2][FUSE ? WREG : 4];
    __shared__ float sdH[4][HR*TC];
    __shared__ float wsl[4], wsd[4];

    const int tid  = threadIdx.x;
    const int wv   = tid >> 6, lane = tid & 63;
    const int Hd = H >> 1, Wd = W >> 1;
    const int ntxy = ntx * nty;

    // exact 1D factor: g_i = row-sum of w25 (k = g g^T since sum k = T^2)
    float g0, g1, g2, g3, g4;
    {
        float gg[5];
#pragma unroll
        for (int i = 0; i < 5; ++i) {
            float s = 0.f;
#pragma unroll
            for (int j = 0; j < 5; ++j) s += w25[i*5 + j];
            gg[i] = s;
        }
        g0 = gg[0]; g1 = gg[1]; g2 = gg[2]; g3 = gg[3]; g4 = gg[4];
    }

    float lsum = 0.f, dsum = 0.f;
    int cur = blockIdx.x;

    // fire-and-forget staging: LDS dest wave-uniform base + lane*16; all
    // addresses CLAMPED in-bounds (garbage in halo; zeroed taps make exact)
    auto stage = [&](int t, int pp) {
        const int n   = t / ntxy;
        const int rem = t - n*ntxy;
        const int ty  = rem / ntx;
        const int tx  = rem - ty*ntx;
        const int gy0 = 2*ty*TR - 2;
        const int gx0 = 2*tx*TC - 4;
        const size_t ib = (size_t)n * H * W;
        for (int j = wv; j < WOPS; j += 4) {
            const int idx4 = j*64 + lane;
            const int r  = idx4 / SEG4;
            const int c4 = idx4 - r*SEG4;
            int gy = gy0 + r;          gy = gy < 0 ? 0 : (gy > H-1 ? H-1 : gy);
            int gx = gx0 + 4*c4;       gx = gx < 0 ? 0 : (gx > W-4 ? W-4 : gx);
            const size_t off = ib + (size_t)gy*W + gx;
            gload_lds16(A + off, &sdA[pp][j*256]);
            if (FUSE) gload_lds16(Bp + off, &sdB[pp][j*256]);
        }
    };

    auto compute = [&](int t, int pp) {
        const int n   = t / ntxy;
        const int rem = t - n*ntxy;
        const int ty  = rem / ntx;
        const int tx  = rem - ty*ntx;
        const float* ax = sdA[pp];
        const float* bx = FUSE ? sdB[pp] : sdA[pp];
        float* hh = sdH[wv];
        const int hb = 8*wv;                 // wave's input-row base
        const bool txL = (tx == 0), txR = (tx == ntx-1);

        // h-pass: 11 rows x 32 even-cols per wave; edge taps zeroed
#pragma unroll
        for (int k = 0; k < (HR*TC + 63)/64; ++k) {
            const int idx = lane + 64*k;
            if (idx < HR*TC) {
                const int hr = idx >> 5, hc = idx & 31;
                const float gl0 = (txL & (hc == 0))  ? 0.f : g0;
                const float gl1 = (txL & (hc == 0))  ? 0.f : g1;
                const float gr4 = (txR & (hc == 31)) ? 0.f : g4;
                const float* pa = &ax[(hb+hr)*COLS + 2*hc + 2];
                float a0 = pa[0], a1 = pa[1], a2 = pa[2], a3 = pa[3], a4 = pa[4];
                if (FUSE) {
                    const float* pb = &bx[(hb+hr)*COLS + 2*hc + 2];
                    a0 -= pb[0]; a1 -= pb[1]; a2 -= pb[2]; a3 -= pb[3]; a4 -= pb[4];
                }
                float h = gl0*a0;
                h = fmaf(gl1, a1, h); h = fmaf(g2, a2, h);
                h = fmaf(g3, a3, h);  h = fmaf(gr4, a4, h);
                hh[hr*TC + hc] = h;
            }
        }
        // v-pass: 2 outputs/lane; top/bottom taps zeroed at image edges
        const int ccx = lane & 31, rsub = lane >> 5;
#pragma unroll
        for (int q = 0; q < 2; ++q) {
            const int lr = rsub + 2*q;                  // 0..3
            const bool mt = (ty == 0) & (wv == 0) & (lr == 0);
            const bool mb = (ty == nty-1) & (wv == 3) & (lr == 3);
            const float gv0 = mt ? 0.f : g0, gv1 = mt ? 0.f : g1;
            const float gv4 = mb ? 0.f : g4;
            float acc = gv0*hh[(2*lr)*TC + ccx];
            acc = fmaf(gv1, hh[(2*lr+1)*TC + ccx], acc);
            acc = fmaf(g2,  hh[(2*lr+2)*TC + ccx], acc);
            acc = fmaf(g3,  hh[(2*lr+3)*TC + ccx], acc);
            acc = fmaf(gv4, hh[(2*lr+4)*TC + ccx], acc);
            if (WRITE_DOWN) {
                const int gr = ty*TR + 4*wv + lr;
                down[(size_t)n*Hd*Wd + (size_t)gr*Wd + (tx*TC + ccx)] = acc;
            }
            // lap = cur - up(down): 2x2 block (always interior -> no mask)
            const int cb = (hb + 2*lr + 2)*COLS + 2*ccx + 4;
            float c0 = ax[cb], c1 = ax[cb+1], c2 = ax[cb+COLS], c3 = ax[cb+COLS+1];
            if (FUSE) {
                c0 -= bx[cb];      c1 -= bx[cb+1];
                c2 -= bx[cb+COLS]; c3 -= bx[cb+COLS+1];
            }
            lsum += fabsf(c0-acc) + fabsf(c1-acc) + fabsf(c2-acc) + fabsf(c3-acc);
            if (LAST) dsum += fabsf(acc);
        }
    };

    if (cur < ntiles) {
        stage(cur, 0);
        int p = 0;
        for (;;) {
            // wait for buf p's loads (issued last iter, aged by compute) and
            // make it visible to all waves
            asm volatile("s_waitcnt vmcnt(0)" ::: "memory");
            __builtin_amdgcn_s_barrier();
            __builtin_amdgcn_sched_barrier(0);

            const int nxt = cur + (int)gridDim.x;
            if (nxt < ntiles) stage(nxt, p ^ 1);   // fire-and-forget prefetch
            __builtin_amdgcn_sched_barrier(0);     // pin issue before compute

            compute(cur, p);

            if (nxt >= ntiles) break;
            cur = nxt; p ^= 1;
        }
    }

    // ---- wave reduce -> block reduce -> one spread atomic per level ----
#pragma unroll
    for (int off = 32; off > 0; off >>= 1) {
        lsum += __shfl_down(lsum, off);
        if (LAST) dsum += __shfl_down(dsum, off);
    }
    __syncthreads();
    if (lane == 0) { wsl[wv] = lsum; if (LAST) wsd[wv] = dsum; }
    __syncthreads();
    if (tid == 0) {
        atomicAdd(&P[level*8 + (blockIdx.x & 7)], wsl[0]+wsl[1]+wsl[2]+wsl[3]);
        if (LAST)
            atomicAdd(&P[24 + (blockIdx.x & 7)], wsd[0]+wsd[1]+wsd[2]+wsd[3]);
    }
}

__global__ void finalize_kernel(const float* __restrict__ P,
                                float* __restrict__ out,
                                float inv0, float inv1, float inv2, float inv3)
{
    float s0 = 0.f, s1 = 0.f, s2 = 0.f, s3 = 0.f;
#pragma unroll
    for (int i = 0; i < 8; ++i) {
        s0 += P[i]; s1 += P[8+i]; s2 += P[16+i]; s3 += P[24+i];
    }
    out[0] = s0*inv0 + s1*inv1 + s2*inv2 + s3*inv3;
}

extern "C" void kernel_launch(void* const* d_in, const int* in_sizes, int n_in,
                              void* d_out, int out_size, void* d_ws, size_t ws_size,
                              hipStream_t stream)
{
    const float* x   = (const float*)d_in[0];
    const float* t   = (const float*)d_in[1];
    const float* ker = (const float*)d_in[2];  // (13,1,5,5); channels identical
    float* out = (float*)d_out;

    constexpr int B = 16, C = 13, H = 512, W = 512;
    constexpr int N = B * C;  // 208 image-channels

    // ws: [32 floats partials (pad 256B)] [down0: N*256*256] [down1: N*128*128]
    float* P     = (float*)d_ws;
    float* down0 = (float*)((char*)d_ws + 256);
    float* down1 = down0 + (size_t)N * (H/2) * (W/2);

    hipMemsetAsync(P, 0, 32 * sizeof(float), stream);

    dim3 blk(THREADS);
    // level 0: FUSE (stages x,t). LDS 46.6 KB -> 3 blocks/CU -> grid 768.
    {
        const int ntx = (W/2)/TC, nty = (H/2)/TR;          // 8 x 16
        lap_level<3, true, false, true><<<dim3(768), blk, 0, stream>>>(
            x, t, ker, down0, P, H, W, ntx, nty, ntx*nty*N, 0);
    }
    // level 1: down0 256 -> down1 128. LDS 25.7 KB -> 6 blocks/CU -> 1536.
    {
        const int ntx = (W/4)/TC, nty = (H/4)/TR;          // 4 x 8
        lap_level<6, false, false, true><<<dim3(1536), blk, 0, stream>>>(
            down0, nullptr, ker, down1, P, H/2, W/2, ntx, nty, ntx*nty*N, 1);
    }
    // level 2: down1 128 -> 64 (in-register), fuses level-3 mean(|down2|)
    {
        const int ntx = (W/8)/TC, nty = (H/8)/TR;          // 2 x 4
        lap_level<6, false, true, false><<<dim3(1536), blk, 0, stream>>>(
            down1, nullptr, ker, nullptr, P, H/4, W/4, ntx, nty, ntx*nty*N, 2);
    }

    const float inv0 = 1.0f / ((float)N * H * W);
    const float inv1 = 1.0f / ((float)N * (H/2) * (W/2));
    const float inv2 = 1.0f / ((float)N * (H/4) * (W/4));
    const float inv3 = 1.0f / ((float)N * (H/8) * (W/8));
    finalize_kernel<<<1, 1, 0, stream>>>(P, out, inv0, inv1, inv2, inv3);
}